// Round 1
// baseline (1151.868 us; speedup 1.0000x reference)
//
#include <hip/hip_runtime.h>
#include <cstddef>

// Problem constants
#define NN   8
#define CIN  1024
#define PL   256
#define PE   1024   // PL*EXP
#define HH   64
#define WW   64
#define HW   4096
#define EPS_ 1e-5f

// Workspace layout (float offsets)
static const size_t WS_POOLED = 0;        // [8][64][1024]  pooled, cell-major (transposed)
static const size_t WS_VEC1   = 524288;   // [8][1024]
static const size_t WS_MASKS  = 532480;   // [8][64] spatial mask (coarse)
static const size_t WS_MC1    = 532992;   // [8][256]
static const size_t WS_VEC2   = 535040;   // [8][256]
static const size_t WS_MC2    = 537088;   // [8][256]
static const size_t WS_S1     = 539136;   // [256]
static const size_t WS_T1     = 539392;   // [256]
static const size_t WS_S2     = 539648;   // [256]
static const size_t WS_T2     = 539904;   // [256]
static const size_t WS_S3     = 540160;   // [1024]
static const size_t WS_T3     = 541184;   // [1024]
static const size_t WS_OUT1   = 542208;   // [8][256][4096]
static const size_t WS_OUT2   = 8930816;  // [8][256][4096]

// Output layout (float offsets in d_out)
static const size_t OUT_MAIN  = 0;          // [8][1024][64][64]
static const size_t OFF1      = 33554432;   // norm_1 [2][9]
static const size_t OFF2      = OFF1 + 18;  // norm_2 [3][9]
static const size_t OFF3      = OFF2 + 27;  // flops  [2][9]

// ---------------- BN fold: scale = g/sqrt(v+eps), shift = b - m*scale ----
__global__ void k_bnfold(const float* __restrict__ bn1, const float* __restrict__ bn2,
                         const float* __restrict__ bn3, float* __restrict__ ws) {
  int i = blockIdx.x * blockDim.x + threadIdx.x;
  if (i < 256) {
    float g = bn1[i], b = bn1[256 + i], m = bn1[512 + i], v = bn1[768 + i];
    float s = g / sqrtf(v + EPS_);
    ws[WS_S1 + i] = s; ws[WS_T1 + i] = b - m * s;
  } else if (i < 512) {
    int c = i - 256;
    float g = bn2[c], b = bn2[256 + c], m = bn2[512 + c], v = bn2[768 + c];
    float s = g / sqrtf(v + EPS_);
    ws[WS_S2 + c] = s; ws[WS_T2 + c] = b - m * s;
  } else if (i < 1536) {
    int c = i - 512;
    float g = bn3[c], b = bn3[1024 + c], m = bn3[2048 + c], v = bn3[3072 + c];
    float s = g / sqrtf(v + EPS_);
    ws[WS_S3 + c] = s; ws[WS_T3 + c] = b - m * s;
  }
}

// ---------------- pool (8x8 avg) + vec1 (global mean), per (n,c) ---------
__global__ __launch_bounds__(64) void k_pool(const float* __restrict__ x, float* __restrict__ ws) {
  const int bx = blockIdx.x;
  const int n = bx >> 10, c = bx & 1023;
  const int t = threadIdx.x;
  const float* xp = x + (size_t)(n * CIN + c) * HW;
  const int g = t >> 3;
  float v1 = 0.f;
  for (int ph = 0; ph < 8; ++ph) {
    float a = 0.f;
#pragma unroll
    for (int r = 0; r < 8; ++r) a += xp[(ph * 8 + r) * 64 + t];
    a += __shfl_xor(a, 1, 64);
    a += __shfl_xor(a, 2, 64);
    a += __shfl_xor(a, 4, 64);   // all lanes in 8-lane group now hold cell sum (ph, g)
    if ((t & 7) == 0)
      ws[WS_POOLED + (size_t)(n * 64 + ph * 8 + g) * 1024 + c] = a * (1.f / 64.f);
    v1 += a;
  }
  v1 += __shfl_xor(v1, 8, 64);
  v1 += __shfl_xor(v1, 16, 64);
  v1 += __shfl_xor(v1, 32, 64);
  if (t == 0) ws[WS_VEC1 + n * 1024 + c] = v1 * (1.f / 4096.f);
}

// ---------------- spatial mask: 3x3 conv on pooled (pad=1) + bias, >=0 ---
__global__ __launch_bounds__(256) void k_masks(const float* __restrict__ wsconv,
                                               const float* __restrict__ wsbias,
                                               float* __restrict__ ws) {
  const int bid = blockIdx.x;
  const int n = bid >> 6, cell = bid & 63, ph = cell >> 3, pw = cell & 7;
  const int tid = threadIdx.x;  // handles c = tid*4 .. tid*4+3
  const float* pooled = ws + WS_POOLED + (size_t)n * 64 * 1024;
  float acc = 0.f;
#pragma unroll
  for (int kh = 0; kh < 3; ++kh) {
    int py = ph + kh - 1;
    if (py < 0 || py > 7) continue;
#pragma unroll
    for (int kw = 0; kw < 3; ++kw) {
      int px = pw + kw - 1;
      if (px < 0 || px > 7) continue;
      float4 pv = *(const float4*)(pooled + (size_t)(py * 8 + px) * 1024 + tid * 4);
      int k = kh * 3 + kw;
      float w0 = wsconv[(tid * 4 + 0) * 9 + k];
      float w1 = wsconv[(tid * 4 + 1) * 9 + k];
      float w2 = wsconv[(tid * 4 + 2) * 9 + k];
      float w3 = wsconv[(tid * 4 + 3) * 9 + k];
      acc += pv.x * w0 + pv.y * w1 + pv.z * w2 + pv.w * w3;
    }
  }
  __shared__ float red[256];
  red[tid] = acc;
  __syncthreads();
  for (int s = 128; s > 0; s >>= 1) {
    if (tid < s) red[tid] += red[tid + s];
    __syncthreads();
  }
  if (tid == 0) {
    float logit = red[0] + wsbias[0];
    ws[WS_MASKS + n * 64 + cell] = (logit >= 0.f) ? 1.f : 0.f;
  }
}

// ---------------- mc1: (vec1 @ wc1^T + bc1) >= 0 -------------------------
__global__ __launch_bounds__(64) void k_mc1(const float* __restrict__ wc1,
                                            const float* __restrict__ bc1,
                                            float* __restrict__ ws) {
  const int bx = blockIdx.x;
  const int n = bx >> 8, p = bx & 255;
  const int t = threadIdx.x;
  const float* v = ws + WS_VEC1 + n * 1024;
  const float* wr = wc1 + (size_t)p * 1024;
  float acc = 0.f;
#pragma unroll
  for (int j = 0; j < 16; ++j) acc += v[t + 64 * j] * wr[t + 64 * j];
  for (int m = 1; m < 64; m <<= 1) acc += __shfl_xor(acc, m, 64);
  if (t == 0) ws[WS_MC1 + n * 256 + p] = (acc + bc1[p] >= 0.f) ? 1.f : 0.f;
}

// ---------------- conv1: 1x1 GEMM (256x4096x1024 per n) + bn1 + relu + gates
__global__ __launch_bounds__(256) void k_conv1(const float* __restrict__ x,
                                               const float* __restrict__ w1,
                                               float* __restrict__ ws) {
  const int h = blockIdx.x, pt = blockIdx.y, n = blockIdx.z;
  const int tx = threadIdx.x, ty = threadIdx.y;
  const int tid = ty * 16 + tx;
  __shared__ float As[16][64];
  __shared__ float Bs[16][64];
  float acc[4][4] = {};
  const float* xb = x + (size_t)n * CIN * HW + h * 64;
  const float* wb = w1 + (size_t)(pt * 64) * CIN;
  const int lp = tid >> 2, lq = (tid & 3) << 2;
  const int lk = tid >> 4, lw = (tid & 15) << 2;
  for (int k0 = 0; k0 < CIN; k0 += 16) {
    float4 av = *(const float4*)(wb + (size_t)lp * CIN + k0 + lq);
    As[lq + 0][lp] = av.x; As[lq + 1][lp] = av.y;
    As[lq + 2][lp] = av.z; As[lq + 3][lp] = av.w;
    *(float4*)&Bs[lk][lw] = *(const float4*)(xb + (size_t)(k0 + lk) * HW + lw);
    __syncthreads();
#pragma unroll
    for (int kk = 0; kk < 16; ++kk) {
      float4 a4 = *(const float4*)&As[kk][ty * 4];
      float4 b4 = *(const float4*)&Bs[kk][tx * 4];
      float a_[4] = {a4.x, a4.y, a4.z, a4.w};
      float b_[4] = {b4.x, b4.y, b4.z, b4.w};
#pragma unroll
      for (int i = 0; i < 4; ++i)
#pragma unroll
        for (int j = 0; j < 4; ++j) acc[i][j] += a_[i] * b_[j];
    }
    __syncthreads();
  }
  const float msp = ws[WS_MASKS + n * 64 + (h >> 3) * 8 + (tx >> 1)];
  float* ob = ws + WS_OUT1 + (size_t)(n * PL) * HW + h * 64 + tx * 4;
#pragma unroll
  for (int i = 0; i < 4; ++i) {
    const int p = pt * 64 + ty * 4 + i;
    const float sc = ws[WS_S1 + p], sh = ws[WS_T1 + p];
    const float gate = ws[WS_MC1 + n * 256 + p] * msp;
    float4 o;
    o.x = fmaxf(fmaf(acc[i][0], sc, sh), 0.f) * gate;
    o.y = fmaxf(fmaf(acc[i][1], sc, sh), 0.f) * gate;
    o.z = fmaxf(fmaf(acc[i][2], sc, sh), 0.f) * gate;
    o.w = fmaxf(fmaf(acc[i][3], sc, sh), 0.f) * gate;
    *(float4*)(ob + (size_t)p * HW) = o;
  }
}

// ---------------- vec2: mean of gated out1 over HW -----------------------
__global__ __launch_bounds__(256) void k_vec2(float* __restrict__ ws) {
  const int bx = blockIdx.x;
  const int n = bx >> 8, p = bx & 255;
  const int tid = threadIdx.x;
  const float* r = ws + WS_OUT1 + (size_t)(n * 256 + p) * HW;
  float acc = 0.f;
#pragma unroll
  for (int j = 0; j < 16; ++j) acc += r[tid + 256 * j];
  for (int m = 1; m < 64; m <<= 1) acc += __shfl_xor(acc, m, 64);
  __shared__ float red[4];
  if ((tid & 63) == 0) red[tid >> 6] = acc;
  __syncthreads();
  if (tid == 0)
    ws[WS_VEC2 + n * 256 + p] = (red[0] + red[1] + red[2] + red[3]) * (1.f / 4096.f);
}

// ---------------- mc2: (vec2 @ wc2^T + bc2) >= 0 -------------------------
__global__ __launch_bounds__(64) void k_mc2(const float* __restrict__ wc2,
                                            const float* __restrict__ bc2,
                                            float* __restrict__ ws) {
  const int bx = blockIdx.x;
  const int n = bx >> 8, p = bx & 255;
  const int t = threadIdx.x;
  const float* v = ws + WS_VEC2 + n * 256;
  const float* wr = wc2 + (size_t)p * 256;
  float acc = 0.f;
#pragma unroll
  for (int j = 0; j < 4; ++j) acc += v[t + 64 * j] * wr[t + 64 * j];
  for (int m = 1; m < 64; m <<= 1) acc += __shfl_xor(acc, m, 64);
  if (t == 0) ws[WS_MC2 + n * 256 + p] = (acc + bc2[p] >= 0.f) ? 1.f : 0.f;
}

// ---------------- conv2: 3x3 (256->256, pad=1) + bn2 + relu + gates ------
__global__ __launch_bounds__(256) void k_conv2(const float* __restrict__ w2,
                                               float* __restrict__ ws) {
  const int h = blockIdx.x, pt = blockIdx.y, n = blockIdx.z;
  const int tx = threadIdx.x, ty = threadIdx.y;
  const int tid = ty * 16 + tx;
  __shared__ float As[9][8][68];   // [tap][cc][p]
  __shared__ float Bs[8][3][68];   // [cc][row][1 + w], halo at 0 and 65
  float acc[4][4] = {};
  const float* in = ws + WS_OUT1 + (size_t)(n * PL) * HW;
  const int pp = tid >> 2, pair = tid & 3;      // A-load role
  const int rid = tid >> 3, lane8 = tid & 7;    // B-load role (tid<192)
  const int ccB = rid / 3, rB = rid % 3;
  for (int c0 = 0; c0 < PL; c0 += 8) {
    // stage weights: As[k][cc][pp] = w2[pt*64+pp][c0+cc][k]
    {
      const float* wsrc = w2 + (size_t)(pt * 64 + pp) * (PL * 9) + c0 * 9 + pair * 18;
      int cc = pair * 2, kidx = 0;
#pragma unroll
      for (int m = 0; m < 18; ++m) {
        As[kidx][cc][pp] = wsrc[m];
        if (++kidx == 9) { kidx = 0; ++cc; }
      }
    }
    // stage input rows h-1..h+1, zero padded
    if (tid < 192) {
      const int hr = h - 1 + rB;
      float4 v0, v1;
      if (hr >= 0 && hr < 64) {
        const float* src = in + (size_t)(c0 + ccB) * HW + hr * 64 + lane8 * 8;
        v0 = *(const float4*)src;
        v1 = *(const float4*)(src + 4);
      } else {
        v0 = make_float4(0.f, 0.f, 0.f, 0.f);
        v1 = v0;
      }
      float* brow = &Bs[ccB][rB][0];
      brow[1 + lane8 * 8 + 0] = v0.x; brow[1 + lane8 * 8 + 1] = v0.y;
      brow[1 + lane8 * 8 + 2] = v0.z; brow[1 + lane8 * 8 + 3] = v0.w;
      brow[1 + lane8 * 8 + 4] = v1.x; brow[1 + lane8 * 8 + 5] = v1.y;
      brow[1 + lane8 * 8 + 6] = v1.z; brow[1 + lane8 * 8 + 7] = v1.w;
      if (lane8 == 0) { brow[0] = 0.f; brow[65] = 0.f; }
    }
    __syncthreads();
#pragma unroll
    for (int cc = 0; cc < 8; ++cc) {
#pragma unroll
      for (int kh = 0; kh < 3; ++kh) {
        const float* brow = &Bs[cc][kh][0];
        float4 b4 = *(const float4*)(brow + tx * 4);
        float b_[6] = {b4.x, b4.y, b4.z, b4.w, brow[tx * 4 + 4], brow[tx * 4 + 5]};
#pragma unroll
        for (int kw = 0; kw < 3; ++kw) {
          float4 a4 = *(const float4*)&As[kh * 3 + kw][cc][ty * 4];
          float a_[4] = {a4.x, a4.y, a4.z, a4.w};
#pragma unroll
          for (int i = 0; i < 4; ++i)
#pragma unroll
            for (int j = 0; j < 4; ++j) acc[i][j] += a_[i] * b_[j + kw];
        }
      }
    }
    __syncthreads();
  }
  const float msp = ws[WS_MASKS + n * 64 + (h >> 3) * 8 + (tx >> 1)];
  float* ob = ws + WS_OUT2 + (size_t)(n * PL) * HW + h * 64 + tx * 4;
#pragma unroll
  for (int i = 0; i < 4; ++i) {
    const int p = pt * 64 + ty * 4 + i;
    const float sc = ws[WS_S2 + p], sh = ws[WS_T2 + p];
    const float gate = ws[WS_MC2 + n * 256 + p] * msp;
    float4 o;
    o.x = fmaxf(fmaf(acc[i][0], sc, sh), 0.f) * gate;
    o.y = fmaxf(fmaf(acc[i][1], sc, sh), 0.f) * gate;
    o.z = fmaxf(fmaf(acc[i][2], sc, sh), 0.f) * gate;
    o.w = fmaxf(fmaf(acc[i][3], sc, sh), 0.f) * gate;
    *(float4*)(ob + (size_t)p * HW) = o;
  }
}

// ---------------- conv3: 1x1 GEMM (1024x4096x256 per n) + bn3*mask + x + relu
__global__ __launch_bounds__(256) void k_conv3(const float* __restrict__ x,
                                               const float* __restrict__ w3,
                                               const float* __restrict__ ws,
                                               float* __restrict__ out) {
  const int h = blockIdx.x, pt = blockIdx.y, n = blockIdx.z;
  const int tx = threadIdx.x, ty = threadIdx.y;
  const int tid = ty * 16 + tx;
  __shared__ float As[16][64];
  __shared__ float Bs[16][64];
  float acc[4][4] = {};
  const float* ib = ws + WS_OUT2 + (size_t)(n * PL) * HW + h * 64;
  const float* wb = w3 + (size_t)(pt * 64) * PL;
  const int lp = tid >> 2, lq = (tid & 3) << 2;
  const int lk = tid >> 4, lw = (tid & 15) << 2;
  for (int k0 = 0; k0 < PL; k0 += 16) {
    float4 av = *(const float4*)(wb + (size_t)lp * PL + k0 + lq);
    As[lq + 0][lp] = av.x; As[lq + 1][lp] = av.y;
    As[lq + 2][lp] = av.z; As[lq + 3][lp] = av.w;
    *(float4*)&Bs[lk][lw] = *(const float4*)(ib + (size_t)(k0 + lk) * HW + lw);
    __syncthreads();
#pragma unroll
    for (int kk = 0; kk < 16; ++kk) {
      float4 a4 = *(const float4*)&As[kk][ty * 4];
      float4 b4 = *(const float4*)&Bs[kk][tx * 4];
      float a_[4] = {a4.x, a4.y, a4.z, a4.w};
      float b_[4] = {b4.x, b4.y, b4.z, b4.w};
#pragma unroll
      for (int i = 0; i < 4; ++i)
#pragma unroll
        for (int j = 0; j < 4; ++j) acc[i][j] += a_[i] * b_[j];
    }
    __syncthreads();
  }
  const float msp = ws[WS_MASKS + n * 64 + (h >> 3) * 8 + (tx >> 1)];
#pragma unroll
  for (int i = 0; i < 4; ++i) {
    const int pe = pt * 64 + ty * 4 + i;
    const float sc = ws[WS_S3 + pe], sh = ws[WS_T3 + pe];
    const size_t off = (size_t)(n * PE + pe) * HW + h * 64 + tx * 4;
    float4 xv = *(const float4*)(x + off);
    float4 o;
    o.x = fmaxf(fmaf(acc[i][0], sc, sh) * msp + xv.x, 0.f);
    o.y = fmaxf(fmaf(acc[i][1], sc, sh) * msp + xv.y, 0.f);
    o.z = fmaxf(fmaf(acc[i][2], sc, sh) * msp + xv.z, 0.f);
    o.w = fmaxf(fmaf(acc[i][3], sc, sh) * msp + xv.w, 0.f);
    *(float4*)(out + off) = o;
  }
}

// ---------------- bookkeeping rows ---------------------------------------
__global__ __launch_bounds__(64) void k_book(const float* __restrict__ n1in,
                                             const float* __restrict__ n2in,
                                             const float* __restrict__ flin,
                                             const float* __restrict__ ws,
                                             float* __restrict__ out) {
  const int t = threadIdx.x;
  if (t < 9) {
    out[OFF1 + t] = n1in[t];
    out[OFF2 + t] = n2in[t];
    out[OFF3 + t] = flin[t];
  }
  if (t < 8) {
    float ns = 0.f, nc1 = 0.f, nc2 = 0.f;
    for (int i = 0; i < 64; ++i) ns += ws[WS_MASKS + t * 64 + i];
    for (int i = 0; i < 256; ++i) nc1 += ws[WS_MC1 + t * 256 + i];
    for (int i = 0; i < 256; ++i) nc2 += ws[WS_MC2 + t * 256 + i];
    out[OFF1 + 9 + t] = ns;
    out[OFF2 + 9 + t] = nc1;
    out[OFF2 + 18 + t] = nc2;
    const float s = ns * 64.f;  // fine-grid spatial mask sum
    // replicate reference association order exactly:
    const float term1 = (s * nc1) * 1024.f;
    const float term2 = ((9.f * s) * nc2) * nc1;
    const float term3 = (s * 1024.f) * nc2;
    out[OFF3 + 9 + t] = (term1 + term2) + term3;
  }
  if (t == 9) {
    out[OFF1 + 17] = 64.f;            // numel_s = 8*8
    out[OFF2 + 17] = 256.f;           // PL
    out[OFF2 + 26] = 256.f;           // PL
    out[OFF3 + 17] = 4563402752.f;    // fl_full (exactly representable: 17*2^28)
  }
}

extern "C" void kernel_launch(void* const* d_in, const int* in_sizes, int n_in,
                              void* d_out, int out_size, void* d_ws, size_t ws_size,
                              hipStream_t stream) {
  (void)in_sizes; (void)n_in; (void)out_size; (void)ws_size;
  const float* x      = (const float*)d_in[0];
  const float* n1in   = (const float*)d_in[1];
  const float* n2in   = (const float*)d_in[2];
  const float* flin   = (const float*)d_in[3];
  const float* wsconv = (const float*)d_in[4];
  const float* wsbias = (const float*)d_in[5];
  const float* wc1    = (const float*)d_in[6];
  const float* bc1    = (const float*)d_in[7];
  const float* wc2    = (const float*)d_in[8];
  const float* bc2    = (const float*)d_in[9];
  const float* w1     = (const float*)d_in[10];
  const float* bn1    = (const float*)d_in[11];
  const float* w2     = (const float*)d_in[12];
  const float* bn2    = (const float*)d_in[13];
  const float* w3     = (const float*)d_in[14];
  const float* bn3    = (const float*)d_in[15];
  float* ws  = (float*)d_ws;
  float* out = (float*)d_out;

  hipLaunchKernelGGL(k_bnfold, dim3(6), dim3(256), 0, stream, bn1, bn2, bn3, ws);
  hipLaunchKernelGGL(k_pool, dim3(NN * CIN), dim3(64), 0, stream, x, ws);
  hipLaunchKernelGGL(k_masks, dim3(NN * 64), dim3(256), 0, stream, wsconv, wsbias, ws);
  hipLaunchKernelGGL(k_mc1, dim3(NN * PL), dim3(64), 0, stream, wc1, bc1, ws);
  hipLaunchKernelGGL(k_conv1, dim3(64, 4, NN), dim3(16, 16), 0, stream, x, w1, ws);
  hipLaunchKernelGGL(k_vec2, dim3(NN * PL), dim3(256), 0, stream, ws);
  hipLaunchKernelGGL(k_mc2, dim3(NN * PL), dim3(64), 0, stream, wc2, bc2, ws);
  hipLaunchKernelGGL(k_conv2, dim3(64, 4, NN), dim3(16, 16), 0, stream, w2, ws);
  hipLaunchKernelGGL(k_conv3, dim3(64, 16, NN), dim3(16, 16), 0, stream, x, w3, ws, out);
  hipLaunchKernelGGL(k_book, dim3(1), dim3(64), 0, stream, n1in, n2in, flin, ws, out);
}

// Round 2
// 685.821 us; speedup vs baseline: 1.6795x; 1.6795x over previous
//
#include <hip/hip_runtime.h>
#include <cstddef>
#include <cstdint>

#define NN   8
#define CIN  1024
#define PL   256
#define PE   1024
#define HW   4096
#define EPS_ 1e-5f

typedef _Float16 half8 __attribute__((ext_vector_type(8)));
typedef float floatx4 __attribute__((ext_vector_type(4)));

union HU { uint4 u4; half8 h8; };

__device__ inline uint32_t pack2(float v) {
  union { _Float16 f[2]; uint32_t u; } z;
  _Float16 h = (_Float16)v;
  z.f[0] = h;
  z.f[1] = (_Float16)(v - (float)h);
  return z.u;
}

// Output tail offsets (float offsets in d_out)
static const size_t OFF1 = 33554432;
static const size_t OFF2 = OFF1 + 18;
static const size_t OFF3 = OFF2 + 27;

// ============ prep: weight splits + bn fold + vec2 zero ==================
__global__ __launch_bounds__(256) void k_prep(
    const float* __restrict__ bn1, const float* __restrict__ bn2,
    const float* __restrict__ bn3, const float* __restrict__ w1,
    const float* __restrict__ w2, const float* __restrict__ w3,
    _Float16* __restrict__ w1h, _Float16* __restrict__ w1l,
    _Float16* __restrict__ w2h, _Float16* __restrict__ w2l,
    _Float16* __restrict__ w3h, _Float16* __restrict__ w3l,
    float* __restrict__ s1, float* __restrict__ t1,
    float* __restrict__ s2, float* __restrict__ t2,
    float* __restrict__ s3, float* __restrict__ t3,
    float* __restrict__ vec2) {
  int idx = blockIdx.x * 256 + threadIdx.x;
  if (idx < 262144) {
    float v = w1[idx]; _Float16 h = (_Float16)v;
    w1h[idx] = h; w1l[idx] = (_Float16)(v - (float)h);
  } else if (idx < 524288) {
    int i = idx - 262144;
    float v = w3[i]; _Float16 h = (_Float16)v;
    w3h[i] = h; w3l[i] = (_Float16)(v - (float)h);
  } else if (idx < 1114112) {
    int i = idx - 524288;
    int tap = i >> 16, rem = i & 65535, p = rem >> 8, c = rem & 255;
    float v = w2[((p << 8) + c) * 9 + tap];
    _Float16 h = (_Float16)v;
    w2h[i] = h; w2l[i] = (_Float16)(v - (float)h);
  } else if (idx < 1116160) {
    vec2[idx - 1114112] = 0.f;
  } else if (idx < 1117696) {
    int i = idx - 1116160;
    if (i < 256) {
      float g = bn1[i], b = bn1[256 + i], m = bn1[512 + i], v = bn1[768 + i];
      float s = g / sqrtf(v + EPS_);
      s1[i] = s; t1[i] = b - m * s;
    } else if (i < 512) {
      int c = i - 256;
      float g = bn2[c], b = bn2[256 + c], m = bn2[512 + c], v = bn2[768 + c];
      float s = g / sqrtf(v + EPS_);
      s2[c] = s; t2[c] = b - m * s;
    } else {
      int c = i - 512;
      float g = bn3[c], b = bn3[1024 + c], m = bn3[2048 + c], v = bn3[3072 + c];
      float s = g / sqrtf(v + EPS_);
      s3[c] = s; t3[c] = b - m * s;
    }
  }
}

// ============ pool (8x8 avg, cell-major) + vec1 ==========================
__global__ __launch_bounds__(64) void k_pool(const float* __restrict__ x,
                                             float* __restrict__ pooled,
                                             float* __restrict__ vec1) {
  const int bx = blockIdx.x;
  const int n = bx >> 10, c = bx & 1023;
  const int t = threadIdx.x;
  const float* xp = x + (size_t)(n * CIN + c) * HW;
  const int g = t >> 3;
  float v1 = 0.f;
  for (int ph = 0; ph < 8; ++ph) {
    float a = 0.f;
#pragma unroll
    for (int r = 0; r < 8; ++r) a += xp[(ph * 8 + r) * 64 + t];
    a += __shfl_xor(a, 1, 64);
    a += __shfl_xor(a, 2, 64);
    a += __shfl_xor(a, 4, 64);
    if ((t & 7) == 0)
      pooled[(size_t)(n * 64 + ph * 8 + g) * 1024 + c] = a * (1.f / 64.f);
    v1 += a;
  }
  v1 += __shfl_xor(v1, 8, 64);
  v1 += __shfl_xor(v1, 16, 64);
  v1 += __shfl_xor(v1, 32, 64);
  if (t == 0) vec1[n * 1024 + c] = v1 * (1.f / 4096.f);
}

// ============ spatial mask ===============================================
__global__ __launch_bounds__(256) void k_masks(const float* __restrict__ wsconv,
                                               const float* __restrict__ wsbias,
                                               const float* __restrict__ pooled,
                                               float* __restrict__ masks) {
  const int bid = blockIdx.x;
  const int n = bid >> 6, cell = bid & 63, ph = cell >> 3, pw = cell & 7;
  const int tid = threadIdx.x;
  const float* pl = pooled + (size_t)n * 64 * 1024;
  float acc = 0.f;
#pragma unroll
  for (int kh = 0; kh < 3; ++kh) {
    int py = ph + kh - 1;
    if (py < 0 || py > 7) continue;
#pragma unroll
    for (int kw = 0; kw < 3; ++kw) {
      int px = pw + kw - 1;
      if (px < 0 || px > 7) continue;
      float4 pv = *(const float4*)(pl + (size_t)(py * 8 + px) * 1024 + tid * 4);
      int k = kh * 3 + kw;
      acc += pv.x * wsconv[(tid * 4 + 0) * 9 + k] + pv.y * wsconv[(tid * 4 + 1) * 9 + k]
           + pv.z * wsconv[(tid * 4 + 2) * 9 + k] + pv.w * wsconv[(tid * 4 + 3) * 9 + k];
    }
  }
  __shared__ float red[256];
  red[tid] = acc;
  __syncthreads();
  for (int s = 128; s > 0; s >>= 1) {
    if (tid < s) red[tid] += red[tid + s];
    __syncthreads();
  }
  if (tid == 0) masks[n * 64 + cell] = (red[0] + wsbias[0] >= 0.f) ? 1.f : 0.f;
}

// ============ mc1 ========================================================
__global__ __launch_bounds__(64) void k_mc1(const float* __restrict__ wc1,
                                            const float* __restrict__ bc1,
                                            const float* __restrict__ vec1,
                                            float* __restrict__ mc1) {
  const int bx = blockIdx.x;
  const int n = bx >> 8, p = bx & 255;
  const int t = threadIdx.x;
  const float* v = vec1 + n * 1024;
  const float* wr = wc1 + (size_t)p * 1024;
  float acc = 0.f;
#pragma unroll
  for (int j = 0; j < 16; ++j) acc += v[t + 64 * j] * wr[t + 64 * j];
  for (int m = 1; m < 64; m <<= 1) acc += __shfl_xor(acc, m, 64);
  if (t == 0) mc1[n * 256 + p] = (acc + bc1[p] >= 0.f) ? 1.f : 0.f;
}

// ============ x -> transposed fp16 hi/lo split ===========================
__global__ __launch_bounds__(256) void k_xsplit(const float* __restrict__ x,
                                                _Float16* __restrict__ xh,
                                                _Float16* __restrict__ xl) {
  const int hw0 = blockIdx.x * 64, c0 = blockIdx.y * 64, n = blockIdx.z;
  const int t = threadIdx.x;
  __shared__ float Tt[64][65];
#pragma unroll
  for (int j = 0; j < 4; ++j) {
    int rc = (t >> 4) + j * 16;
    int col = (t & 15) * 4;
    float4 v = *(const float4*)(x + ((size_t)(n * 1024) + c0 + rc) * 4096 + hw0 + col);
    Tt[col + 0][rc] = v.x; Tt[col + 1][rc] = v.y;
    Tt[col + 2][rc] = v.z; Tt[col + 3][rc] = v.w;
  }
  __syncthreads();
  const int hwl = t >> 2, part = t & 3;
  size_t ob = ((size_t)(n * 4096) + hw0 + hwl) * 1024 + c0 + part * 16;
#pragma unroll
  for (int k2 = 0; k2 < 2; ++k2) {
    half8 vh, vl;
#pragma unroll
    for (int e = 0; e < 8; ++e) {
      float v = Tt[hwl][part * 16 + k2 * 8 + e];
      _Float16 hh = (_Float16)v;
      vh[e] = hh; vl[e] = (_Float16)(v - (float)hh);
    }
    *(half8*)(xh + ob + k2 * 8) = vh;
    *(half8*)(xl + ob + k2 * 8) = vl;
  }
}

// ============ conv1: MFMA GEMM 256x(8*4096)x1024 + bn1/relu/gates ========
// writes out1T[hw][p] fp16 hi/lo
__global__ __launch_bounds__(256) void k_gemm1(
    const _Float16* __restrict__ xh, const _Float16* __restrict__ xl,
    const _Float16* __restrict__ w1h, const _Float16* __restrict__ w1l,
    const float* __restrict__ s1, const float* __restrict__ t1,
    const float* __restrict__ mc1, const float* __restrict__ masks,
    _Float16* __restrict__ o1h, _Float16* __restrict__ o1l) {
  const int hw0 = blockIdx.x * 128, p0 = blockIdx.y * 128, n = blockIdx.z;
  const int t = threadIdx.x;
  const int lane = t & 63, w = t >> 6;
  const int l15 = lane & 15, l4 = lane >> 4;
  const int wr = w >> 1, wc = w & 1;
  __shared__ __align__(16) char smem[40960];
  _Float16* LB = (_Float16*)smem;  // Ah 0, Al 5120, Bh 10240, Bl 15360 (halfs)
  floatx4 acc[4][4] = {};
  const size_t nb = (size_t)(n * 4096) + hw0;
  for (int ks = 0; ks < 32; ++ks) {
    const int c0 = ks * 32;
    half8 tmp[8];
#pragma unroll
    for (int j = 0; j < 8; ++j) {
      int u = t + 256 * j;
      int kind = u >> 9, rem = u & 511, row = rem >> 2, q = rem & 3;
      const _Float16* src;
      if (kind == 0)      src = w1h + (size_t)(p0 + row) * 1024 + c0 + q * 8;
      else if (kind == 1) src = w1l + (size_t)(p0 + row) * 1024 + c0 + q * 8;
      else if (kind == 2) src = xh + (nb + row) * 1024 + c0 + q * 8;
      else                src = xl + (nb + row) * 1024 + c0 + q * 8;
      tmp[j] = *(const half8*)src;
    }
    __syncthreads();
#pragma unroll
    for (int j = 0; j < 8; ++j) {
      int u = t + 256 * j;
      int kind = u >> 9, rem = u & 511, row = rem >> 2, q = rem & 3;
      *(half8*)(LB + kind * 5120 + row * 40 + q * 8) = tmp[j];
    }
    __syncthreads();
    half8 ah[4], al[4], bh[4], bl[4];
#pragma unroll
    for (int i = 0; i < 4; ++i) {
      int r = (wr * 64 + i * 16 + l15) * 40 + l4 * 8;
      ah[i] = *(const half8*)(LB + r);
      al[i] = *(const half8*)(LB + 5120 + r);
    }
#pragma unroll
    for (int j = 0; j < 4; ++j) {
      int r = (wc * 64 + j * 16 + l15) * 40 + l4 * 8;
      bh[j] = *(const half8*)(LB + 10240 + r);
      bl[j] = *(const half8*)(LB + 15360 + r);
    }
#pragma unroll
    for (int i = 0; i < 4; ++i)
#pragma unroll
      for (int j = 0; j < 4; ++j) {
        acc[i][j] = __builtin_amdgcn_mfma_f32_16x16x32_f16(ah[i], bh[j], acc[i][j], 0, 0, 0);
        acc[i][j] = __builtin_amdgcn_mfma_f32_16x16x32_f16(ah[i], bl[j], acc[i][j], 0, 0, 0);
        acc[i][j] = __builtin_amdgcn_mfma_f32_16x16x32_f16(al[i], bh[j], acc[i][j], 0, 0, 0);
      }
  }
  // epilogue: bn1+relu+gates, transpose via LDS, store fp16 hi/lo
  uint32_t (*T)[132] = (uint32_t(*)[132])smem;
  const int n64 = n * 64;
  const float* mc1n = mc1 + n * 256;
  for (int h = 0; h < 2; ++h) {
    __syncthreads();
    if (wc == h) {
#pragma unroll
      for (int j = 0; j < 4; ++j) {
        int nl = j * 16 + l15;
        int pix = hw0 + h * 64 + nl;
        float msk = masks[n64 + ((pix >> 9) << 3) + ((pix & 63) >> 3)];
#pragma unroll
        for (int i = 0; i < 4; ++i) {
          uint32_t pk[4];
#pragma unroll
          for (int r = 0; r < 4; ++r) {
            int m = wr * 64 + i * 16 + l4 * 4 + r;
            int p = p0 + m;
            float val = fmaxf(fmaf(acc[i][j][r], s1[p], t1[p]), 0.f) * (mc1n[p] * msk);
            pk[r] = pack2(val);
          }
          *(uint4*)&T[nl][wr * 64 + i * 16 + l4 * 4] = *(uint4*)pk;
        }
      }
    }
    __syncthreads();
    {
      int row = t >> 2, seg = t & 3;
      int pix = hw0 + h * 64 + row;
      _Float16* dh = o1h + ((size_t)(n * 4096) + pix) * 256 + p0 + seg * 32;
      _Float16* dl = o1l + ((size_t)(n * 4096) + pix) * 256 + p0 + seg * 32;
#pragma unroll
      for (int k2 = 0; k2 < 4; ++k2) {
        uint4 a = *(uint4*)&T[row][seg * 32 + k2 * 8];
        uint4 b = *(uint4*)&T[row][seg * 32 + k2 * 8 + 4];
        uint4 hv = make_uint4((a.x & 0xFFFFu) | (a.y << 16), (a.z & 0xFFFFu) | (a.w << 16),
                              (b.x & 0xFFFFu) | (b.y << 16), (b.z & 0xFFFFu) | (b.w << 16));
        uint4 lv = make_uint4((a.x >> 16) | (a.y & 0xFFFF0000u), (a.z >> 16) | (a.w & 0xFFFF0000u),
                              (b.x >> 16) | (b.y & 0xFFFF0000u), (b.z >> 16) | (b.w & 0xFFFF0000u));
        *(uint4*)(dh + k2 * 8) = hv;
        *(uint4*)(dl + k2 * 8) = lv;
      }
    }
  }
}

// ============ vec2 =======================================================
__global__ __launch_bounds__(256) void k_vec2(const _Float16* __restrict__ o1h,
                                              const _Float16* __restrict__ o1l,
                                              float* __restrict__ vec2) {
  const int n = blockIdx.x >> 5, ch = blockIdx.x & 31;
  const int t = threadIdx.x;
  const _Float16* bh = o1h + ((size_t)(n * 4096) + ch * 128) * 256 + t;
  const _Float16* bl = o1l + ((size_t)(n * 4096) + ch * 128) * 256 + t;
  float s = 0.f;
  for (int i = 0; i < 128; ++i)
    s += (float)bh[(size_t)i * 256] + (float)bl[(size_t)i * 256];
  atomicAdd(&vec2[n * 256 + t], s * (1.f / 4096.f));
}

// ============ mc2 ========================================================
__global__ __launch_bounds__(64) void k_mc2(const float* __restrict__ wc2,
                                            const float* __restrict__ bc2,
                                            const float* __restrict__ vec2,
                                            float* __restrict__ mc2) {
  const int bx = blockIdx.x;
  const int n = bx >> 8, p = bx & 255;
  const int t = threadIdx.x;
  const float* v = vec2 + n * 256;
  const float* wr = wc2 + (size_t)p * 256;
  float acc = 0.f;
#pragma unroll
  for (int j = 0; j < 4; ++j) acc += v[t + 64 * j] * wr[t + 64 * j];
  for (int m = 1; m < 64; m <<= 1) acc += __shfl_xor(acc, m, 64);
  if (t == 0) mc2[n * 256 + p] = (acc + bc2[p] >= 0.f) ? 1.f : 0.f;
}

// ============ conv2: 3x3 MFMA, 9 taps as accumulated GEMMs ===============
__global__ __launch_bounds__(256) void k_gemm2(
    const _Float16* __restrict__ o1h, const _Float16* __restrict__ o1l,
    const _Float16* __restrict__ w2h, const _Float16* __restrict__ w2l,
    const float* __restrict__ s2, const float* __restrict__ t2,
    const float* __restrict__ mc2, const float* __restrict__ masks,
    _Float16* __restrict__ o2h, _Float16* __restrict__ o2l) {
  const int bt = blockIdx.x, p0 = blockIdx.y * 128, n = blockIdx.z;
  const int hw0 = bt * 128;
  const int t = threadIdx.x;
  const int lane = t & 63, w = t >> 6;
  const int l15 = lane & 15, l4 = lane >> 4;
  const int wr = w >> 1, wc = w & 1;
  // LDS: Sh 0 (264*40), Sl 10560, Ah 21120, Al 26240  (halfs); total 62720 B
  __shared__ __align__(16) char smem[62720];
  _Float16* LB = (_Float16*)smem;
  floatx4 acc[4][4] = {};
  const size_t onb = (size_t)(n * 4096);
  const int row0 = bt * 2 - 1;  // strip top image row
  for (int c0 = 0; c0 < 256; c0 += 32) {
    // ---- stage haloed strip: 4 rows x 66 cols x 32 ch, hi+lo ----
    HU st[9];
#pragma unroll
    for (int j2 = 0; j2 < 9; ++j2) {
      int u = t + 256 * j2;
      st[j2].u4 = make_uint4(0u, 0u, 0u, 0u);
      if (u < 2112) {
        int kind = (u >= 1056) ? 1 : 0;
        int rem = u - kind * 1056;
        int pix = rem >> 2, q = rem & 3;
        int sr = pix / 66, sc = pix - sr * 66;
        int gr = row0 + sr, gc = sc - 1;
        if (gr >= 0 && gr < 64 && gc >= 0 && gc < 64) {
          const _Float16* src = (kind ? o1l : o1h) + (onb + gr * 64 + gc) * 256 + c0 + q * 8;
          st[j2].h8 = *(const half8*)src;
        }
      }
    }
    __syncthreads();
#pragma unroll
    for (int j2 = 0; j2 < 9; ++j2) {
      int u = t + 256 * j2;
      if (u < 2112) {
        int kind = (u >= 1056) ? 1 : 0;
        int rem = u - kind * 1056;
        int pix = rem >> 2, q = rem & 3;
        *(half8*)(LB + kind * 10560 + pix * 40 + q * 8) = st[j2].h8;
      }
    }
    for (int tap = 0; tap < 9; ++tap) {
      const int kh = tap / 3, kw = tap - kh * 3;
      HU at[4];
#pragma unroll
      for (int j2 = 0; j2 < 4; ++j2) {
        int u = t + 256 * j2;
        int kind = u >> 9, rem = u & 511, row = rem >> 2, q = rem & 3;
        const _Float16* src = (kind ? w2l : w2h) + (size_t)tap * 65536 +
                              (size_t)(p0 + row) * 256 + c0 + q * 8;
        at[j2].h8 = *(const half8*)src;
      }
      __syncthreads();  // prior tap's reads done (tap0: strip writes ordered too)
#pragma unroll
      for (int j2 = 0; j2 < 4; ++j2) {
        int u = t + 256 * j2;
        int kind = u >> 9, rem = u & 511, row = rem >> 2, q = rem & 3;
        *(half8*)(LB + 21120 + kind * 5120 + row * 40 + q * 8) = at[j2].h8;
      }
      __syncthreads();
      half8 ah[4], al[4], bh[4], bl[4];
#pragma unroll
      for (int i = 0; i < 4; ++i) {
        int r = (wr * 64 + i * 16 + l15) * 40 + l4 * 8;
        ah[i] = *(const half8*)(LB + 21120 + r);
        al[i] = *(const half8*)(LB + 26240 + r);
      }
#pragma unroll
      for (int j = 0; j < 4; ++j) {
        int nl = wc * 64 + j * 16 + l15;
        int pi = ((nl >> 6) + kh) * 66 + (nl & 63) + kw;
        bh[j] = *(const half8*)(LB + pi * 40 + l4 * 8);
        bl[j] = *(const half8*)(LB + 10560 + pi * 40 + l4 * 8);
      }
#pragma unroll
      for (int i = 0; i < 4; ++i)
#pragma unroll
        for (int j = 0; j < 4; ++j) {
          acc[i][j] = __builtin_amdgcn_mfma_f32_16x16x32_f16(ah[i], bh[j], acc[i][j], 0, 0, 0);
          acc[i][j] = __builtin_amdgcn_mfma_f32_16x16x32_f16(ah[i], bl[j], acc[i][j], 0, 0, 0);
          acc[i][j] = __builtin_amdgcn_mfma_f32_16x16x32_f16(al[i], bh[j], acc[i][j], 0, 0, 0);
        }
    }
    __syncthreads();  // strip reads done before next chunk overwrites
  }
  // epilogue: bn2+relu+gates -> out2T fp16 hi/lo
  uint32_t (*T)[132] = (uint32_t(*)[132])smem;
  const int n64 = n * 64;
  const float* mc2n = mc2 + n * 256;
  for (int h = 0; h < 2; ++h) {
    __syncthreads();
    if (wc == h) {
#pragma unroll
      for (int j = 0; j < 4; ++j) {
        int nl = j * 16 + l15;
        int pix = hw0 + h * 64 + nl;
        float msk = masks[n64 + ((pix >> 9) << 3) + ((pix & 63) >> 3)];
#pragma unroll
        for (int i = 0; i < 4; ++i) {
          uint32_t pk[4];
#pragma unroll
          for (int r = 0; r < 4; ++r) {
            int m = wr * 64 + i * 16 + l4 * 4 + r;
            int p = p0 + m;
            float val = fmaxf(fmaf(acc[i][j][r], s2[p], t2[p]), 0.f) * (mc2n[p] * msk);
            pk[r] = pack2(val);
          }
          *(uint4*)&T[nl][wr * 64 + i * 16 + l4 * 4] = *(uint4*)pk;
        }
      }
    }
    __syncthreads();
    {
      int row = t >> 2, seg = t & 3;
      int pix = hw0 + h * 64 + row;
      _Float16* dh = o2h + ((size_t)(n * 4096) + pix) * 256 + p0 + seg * 32;
      _Float16* dl = o2l + ((size_t)(n * 4096) + pix) * 256 + p0 + seg * 32;
#pragma unroll
      for (int k2 = 0; k2 < 4; ++k2) {
        uint4 a = *(uint4*)&T[row][seg * 32 + k2 * 8];
        uint4 b = *(uint4*)&T[row][seg * 32 + k2 * 8 + 4];
        uint4 hv = make_uint4((a.x & 0xFFFFu) | (a.y << 16), (a.z & 0xFFFFu) | (a.w << 16),
                              (b.x & 0xFFFFu) | (b.y << 16), (b.z & 0xFFFFu) | (b.w << 16));
        uint4 lv = make_uint4((a.x >> 16) | (a.y & 0xFFFF0000u), (a.z >> 16) | (a.w & 0xFFFF0000u),
                              (b.x >> 16) | (b.y & 0xFFFF0000u), (b.z >> 16) | (b.w & 0xFFFF0000u));
        *(uint4*)(dh + k2 * 8) = hv;
        *(uint4*)(dl + k2 * 8) = lv;
      }
    }
  }
}

// ============ conv3: MFMA GEMM 1024x(8*4096)x256 + bn3*mask + x + relu ===
__global__ __launch_bounds__(256) void k_gemm3(
    const _Float16* __restrict__ o2h, const _Float16* __restrict__ o2l,
    const _Float16* __restrict__ w3h, const _Float16* __restrict__ w3l,
    const float* __restrict__ s3, const float* __restrict__ t3,
    const float* __restrict__ masks, const float* __restrict__ x,
    float* __restrict__ out) {
  const int hw0 = blockIdx.x * 128, p0 = blockIdx.y * 128, n = blockIdx.z;
  const int t = threadIdx.x;
  const int lane = t & 63, w = t >> 6;
  const int l15 = lane & 15, l4 = lane >> 4;
  const int wr = w >> 1, wc = w & 1;
  __shared__ __align__(16) char smem[40960];
  _Float16* LB = (_Float16*)smem;
  floatx4 acc[4][4] = {};
  const size_t nb = (size_t)(n * 4096) + hw0;
  for (int ks = 0; ks < 8; ++ks) {
    const int c0 = ks * 32;
    half8 tmp[8];
#pragma unroll
    for (int j = 0; j < 8; ++j) {
      int u = t + 256 * j;
      int kind = u >> 9, rem = u & 511, row = rem >> 2, q = rem & 3;
      const _Float16* src;
      if (kind == 0)      src = w3h + (size_t)(p0 + row) * 256 + c0 + q * 8;
      else if (kind == 1) src = w3l + (size_t)(p0 + row) * 256 + c0 + q * 8;
      else if (kind == 2) src = o2h + (nb + row) * 256 + c0 + q * 8;
      else                src = o2l + (nb + row) * 256 + c0 + q * 8;
      tmp[j] = *(const half8*)src;
    }
    __syncthreads();
#pragma unroll
    for (int j = 0; j < 8; ++j) {
      int u = t + 256 * j;
      int kind = u >> 9, rem = u & 511, row = rem >> 2, q = rem & 3;
      *(half8*)(LB + kind * 5120 + row * 40 + q * 8) = tmp[j];
    }
    __syncthreads();
    half8 ah[4], al[4], bh[4], bl[4];
#pragma unroll
    for (int i = 0; i < 4; ++i) {
      int r = (wr * 64 + i * 16 + l15) * 40 + l4 * 8;
      ah[i] = *(const half8*)(LB + r);
      al[i] = *(const half8*)(LB + 5120 + r);
    }
#pragma unroll
    for (int j = 0; j < 4; ++j) {
      int r = (wc * 64 + j * 16 + l15) * 40 + l4 * 8;
      bh[j] = *(const half8*)(LB + 10240 + r);
      bl[j] = *(const half8*)(LB + 15360 + r);
    }
#pragma unroll
    for (int i = 0; i < 4; ++i)
#pragma unroll
      for (int j = 0; j < 4; ++j) {
        acc[i][j] = __builtin_amdgcn_mfma_f32_16x16x32_f16(ah[i], bh[j], acc[i][j], 0, 0, 0);
        acc[i][j] = __builtin_amdgcn_mfma_f32_16x16x32_f16(ah[i], bl[j], acc[i][j], 0, 0, 0);
        acc[i][j] = __builtin_amdgcn_mfma_f32_16x16x32_f16(al[i], bh[j], acc[i][j], 0, 0, 0);
      }
  }
  const int n64 = n * 64;
  float msk[4];
#pragma unroll
  for (int j = 0; j < 4; ++j) {
    int pix = hw0 + wc * 64 + j * 16 + l15;
    msk[j] = masks[n64 + ((pix >> 9) << 3) + ((pix & 63) >> 3)];
  }
#pragma unroll
  for (int i = 0; i < 4; ++i)
#pragma unroll
    for (int r = 0; r < 4; ++r) {
      int m = wr * 64 + i * 16 + l4 * 4 + r;
      int pe = p0 + m;
      float sc = s3[pe], sh = t3[pe];
      size_t rowoff = ((size_t)(n * 1024) + pe) * 4096 + hw0;
#pragma unroll
      for (int j = 0; j < 4; ++j) {
        int nl = wc * 64 + j * 16 + l15;
        float val = fmaf(acc[i][j][r], sc, sh) * msk[j];
        size_t off = rowoff + nl;
        out[off] = fmaxf(val + x[off], 0.f);
      }
    }
}

// ============ bookkeeping ================================================
__global__ __launch_bounds__(64) void k_book(const float* __restrict__ n1in,
                                             const float* __restrict__ n2in,
                                             const float* __restrict__ flin,
                                             const float* __restrict__ masks,
                                             const float* __restrict__ mc1,
                                             const float* __restrict__ mc2,
                                             float* __restrict__ out) {
  const int t = threadIdx.x;
  if (t < 9) {
    out[OFF1 + t] = n1in[t];
    out[OFF2 + t] = n2in[t];
    out[OFF3 + t] = flin[t];
  }
  if (t < 8) {
    float ns = 0.f, nc1 = 0.f, nc2 = 0.f;
    for (int i = 0; i < 64; ++i) ns += masks[t * 64 + i];
    for (int i = 0; i < 256; ++i) nc1 += mc1[t * 256 + i];
    for (int i = 0; i < 256; ++i) nc2 += mc2[t * 256 + i];
    out[OFF1 + 9 + t] = ns;
    out[OFF2 + 9 + t] = nc1;
    out[OFF2 + 18 + t] = nc2;
    const float s = ns * 64.f;
    const float term1 = (s * nc1) * 1024.f;
    const float term2 = ((9.f * s) * nc2) * nc1;
    const float term3 = (s * 1024.f) * nc2;
    out[OFF3 + 9 + t] = (term1 + term2) + term3;
  }
  if (t == 9) {
    out[OFF1 + 17] = 64.f;
    out[OFF2 + 17] = 256.f;
    out[OFF2 + 26] = 256.f;
    out[OFF3 + 17] = 4563402752.f;
  }
}

extern "C" void kernel_launch(void* const* d_in, const int* in_sizes, int n_in,
                              void* d_out, int out_size, void* d_ws, size_t ws_size,
                              hipStream_t stream) {
  (void)in_sizes; (void)n_in; (void)out_size; (void)ws_size;
  const float* x      = (const float*)d_in[0];
  const float* n1in   = (const float*)d_in[1];
  const float* n2in   = (const float*)d_in[2];
  const float* flin   = (const float*)d_in[3];
  const float* wsconv = (const float*)d_in[4];
  const float* wsbias = (const float*)d_in[5];
  const float* wc1    = (const float*)d_in[6];
  const float* bc1    = (const float*)d_in[7];
  const float* wc2    = (const float*)d_in[8];
  const float* bc2    = (const float*)d_in[9];
  const float* w1     = (const float*)d_in[10];
  const float* bn1    = (const float*)d_in[11];
  const float* w2     = (const float*)d_in[12];
  const float* bn2    = (const float*)d_in[13];
  const float* w3     = (const float*)d_in[14];
  const float* bn3    = (const float*)d_in[15];
  float* out = (float*)d_out;

  // xT hi/lo live in the (not-yet-written) main-out region of d_out: 134,217,728 B
  _Float16* xh = (_Float16*)d_out;
  _Float16* xl = xh + 33554432;

  char* W = (char*)d_ws;
  _Float16* o1h = (_Float16*)(W);
  _Float16* o1l = (_Float16*)(W + 16777216);
  _Float16* o2h = (_Float16*)(W + 33554432);
  _Float16* o2l = (_Float16*)(W + 50331648);
  _Float16* w1h = (_Float16*)(W + 67108864);
  _Float16* w1l = (_Float16*)(W + 67633152);
  _Float16* w2h = (_Float16*)(W + 68157440);
  _Float16* w2l = (_Float16*)(W + 69337088);
  _Float16* w3h = (_Float16*)(W + 70516736);
  _Float16* w3l = (_Float16*)(W + 71041024);
  float* pooled = (float*)(W + 71565312);
  float* vec1   = (float*)(W + 73662464);
  float* vec2   = (float*)(W + 73695232);
  float* masksP = (float*)(W + 73703424);
  float* mc1    = (float*)(W + 73705472);
  float* mc2    = (float*)(W + 73713664);
  float* s1     = (float*)(W + 73721856);
  float* t1     = (float*)(W + 73722880);
  float* s2     = (float*)(W + 73723904);
  float* t2     = (float*)(W + 73724928);
  float* s3     = (float*)(W + 73725952);
  float* t3     = (float*)(W + 73730048);

  hipLaunchKernelGGL(k_prep, dim3(4366), dim3(256), 0, stream,
                     bn1, bn2, bn3, w1, w2, w3, w1h, w1l, w2h, w2l, w3h, w3l,
                     s1, t1, s2, t2, s3, t3, vec2);
  hipLaunchKernelGGL(k_pool, dim3(NN * CIN), dim3(64), 0, stream, x, pooled, vec1);
  hipLaunchKernelGGL(k_masks, dim3(NN * 64), dim3(256), 0, stream, wsconv, wsbias, pooled, masksP);
  hipLaunchKernelGGL(k_mc1, dim3(NN * PL), dim3(64), 0, stream, wc1, bc1, vec1, mc1);
  hipLaunchKernelGGL(k_xsplit, dim3(64, 16, NN), dim3(256), 0, stream, x, xh, xl);
  hipLaunchKernelGGL(k_gemm1, dim3(32, 2, NN), dim3(256), 0, stream,
                     xh, xl, w1h, w1l, s1, t1, mc1, masksP, o1h, o1l);
  hipLaunchKernelGGL(k_vec2, dim3(NN * 32), dim3(256), 0, stream, o1h, o1l, vec2);
  hipLaunchKernelGGL(k_mc2, dim3(NN * PL), dim3(64), 0, stream, wc2, bc2, vec2, mc2);
  hipLaunchKernelGGL(k_gemm2, dim3(32, 2, NN), dim3(256), 0, stream,
                     o1h, o1l, w2h, w2l, s2, t2, mc2, masksP, o2h, o2l);
  hipLaunchKernelGGL(k_gemm3, dim3(32, 8, NN), dim3(256), 0, stream,
                     o2h, o2l, w3h, w3l, s3, t3, masksP, x, out);
  hipLaunchKernelGGL(k_book, dim3(1), dim3(64), 0, stream,
                     n1in, n2in, flin, masksP, mc1, mc2, out);
}